// Round 7
// baseline (553.039 us; speedup 1.0000x reference)
//
#include <hip/hip_runtime.h>
#include <math.h>
#include <limits.h>

// ---------------- helpers ----------------

__device__ __forceinline__ float wredsum(float v) {
#pragma unroll
    for (int off = 32; off > 0; off >>= 1) v += __shfl_xor(v, off, 64);
    return v;
}

__device__ __forceinline__ float rdlane_f(float v, int i) {
    return __uint_as_float(__builtin_amdgcn_readlane(__float_as_uint(v), i));
}

// artanh for z >= 0, clipped like the reference (1 - 1e-7), accurate for tiny z
__device__ __forceinline__ float artanh_pos(float z) {
    z = fminf(z, 1.0f - 1e-7f);
    return 0.5f * (log1pf(z) - log1pf(-z));
}

// fp32 <-> bf16 (round-to-nearest-even)
__device__ __forceinline__ unsigned short f2bf(float f) {
    unsigned u = __float_as_uint(f);
    unsigned r = 0x7FFFu + ((u >> 16) & 1u);
    return (unsigned short)((u + r) >> 16);
}
__device__ __forceinline__ float bf2f(unsigned short h) {
    return __uint_as_float(((unsigned)h) << 16);
}

#define MAXNORM 0.996f   // (1 - 4e-3)/sqrt(c), c = 1
#define MINNORM 1e-15f

// ---------------- kernel 1: utx = logmap0(hyp_linear(x,W,b)) ----------------
// lane = row, 64 rows per BLOCK; the block's 4 waves split K (32 floats each)
// and reduce partial acc[64] + xsq through LDS into wave 0, which runs the
// epilogue. W reads stay wave-uniform (readfirstlane-pinned) -> s_load path.
// Writes fp32 utx (score path, bit-exact) AND bf16 utx16 (bulk gather paths).

__global__ __launch_bounds__(256) void k_linear(
    const float* __restrict__ x, const float* __restrict__ Wg,
    const float* __restrict__ b, float* __restrict__ utx,
    unsigned short* __restrict__ utx16, int N)
{
    __shared__ float hb_s[64];
    __shared__ float red[3][16][64];   // 12 KB: 16-reg chunks, lane-contiguous (conflict-free)
    __shared__ float xq_s[3][64];
    int tid = threadIdx.x;
    int wave = tid >> 6, lane = tid & 63;
    int wave_u = __builtin_amdgcn_readfirstlane(wave);  // keep W addressing scalar

    if (wave == 0) {
        // hb = proj(expmap0(b)) : 64-dim (lane = dim)
        float bv = b[lane];
        float bn = fmaxf(sqrtf(wredsum(bv * bv)), MINNORM);
        float h = tanhf(bn) / bn * bv;
        float hn = fmaxf(sqrtf(wredsum(h * h)), MINNORM);
        if (hn > MAXNORM) h *= MAXNORM / hn;
        hb_s[lane] = h;
    }
    __syncthreads();

    int row = blockIdx.x * 64 + lane;
    bool valid = row < N;
    int srow = valid ? row : (N - 1);
    const float* xr = x + (size_t)srow * 128 + wave_u * 32;
    const float* wr = Wg + wave_u * 32;

    float acc[64];
#pragma unroll
    for (int o = 0; o < 64; ++o) acc[o] = 0.f;
    float xsq = 0.f;

    for (int jt = 0; jt < 8; ++jt) {             // this wave's quarter of K
        float4 xv = *(const float4*)(xr + jt * 4);
        xsq += xv.x * xv.x + xv.y * xv.y + xv.z * xv.z + xv.w * xv.w;
#pragma unroll
        for (int o = 0; o < 64; ++o) {           // wave-uniform -> s_load
            float4 wv = *(const float4*)(wr + o * 128 + jt * 4);
            acc[o] += xv.x * wv.x + xv.y * wv.y + xv.z * wv.z + xv.w * wv.w;
        }
    }

    // ---- cross-wave reduction (fixed order -> deterministic) ----
    if (wave_u != 0) xq_s[wave_u - 1][lane] = xsq;
#pragma unroll
    for (int c = 0; c < 4; ++c) {
        if (wave_u != 0) {
#pragma unroll
            for (int r = 0; r < 16; ++r) red[wave_u - 1][r][lane] = acc[c * 16 + r];
        }
        __syncthreads();
        if (wave_u == 0) {
#pragma unroll
            for (int r = 0; r < 16; ++r)
                acc[c * 16 + r] += red[0][r][lane] + red[1][r][lane] + red[2][r][lane];
        }
        __syncthreads();
    }
    if (wave_u != 0) return;                     // epilogue is wave 0 only
    xsq += xq_s[0][lane] + xq_s[1][lane] + xq_s[2][lane];

    // ---- epilogue, all per-lane scalar ----
    float mx2 = 0.f;
#pragma unroll
    for (int o = 0; o < 64; ++o) mx2 += acc[o] * acc[o];

    float xn  = fmaxf(sqrtf(xsq), MINNORM);
    float mxn = fmaxf(sqrtf(mx2), MINNORM);
    float fac = tanhf(mxn / xn * artanh_pos(xn)) / mxn;   // mobius_matvec scale
    float rn  = fac * mxn;                                // ||res||
    if (rn > MAXNORM) { fac *= MAXNORM / rn; rn = MAXNORM; }  // proj
    float x2 = rn * rn;

    // hb2 = ||hb||^2 (wave-uniform)
    float hv_ = hb_s[lane];
    float hb2 = wredsum(hv_ * hv_);

    // mobius_add(res, hb): xy = <res, hb>
    float xy = 0.f;
#pragma unroll
    for (int o = 0; o < 64; ++o) xy += (fac * acc[o]) * hb_s[o];

    float den = fmaxf(1.f + 2.f * xy + x2 * hb2, MINNORM);
    float ca  = (1.f + 2.f * xy + hb2) / den;   // coeff on res
    float cb  = (1.f - x2) / den;               // coeff on hb

    float pn2 = 0.f;
#pragma unroll
    for (int o = 0; o < 64; ++o) {
        float p = ca * (fac * acc[o]) + cb * hb_s[o];
        acc[o] = p;
        pn2 += p * p;
    }
    float pn  = fmaxf(sqrtf(pn2), MINNORM);
    float psc = (pn > MAXNORM) ? (MAXNORM / pn) : 1.0f;   // proj
    float qn  = fmaxf(pn * psc, MINNORM);
    float lfac = artanh_pos(qn) / qn * psc;               // logmap0 scale

    if (valid) {
        float* orow = utx + (size_t)row * 64;
        unsigned short* orow16 = utx16 + (size_t)row * 64;
#pragma unroll
        for (int o = 0; o < 64; o += 4) {
            float4 ov = { acc[o] * lfac, acc[o + 1] * lfac,
                          acc[o + 2] * lfac, acc[o + 3] * lfac };
            *(float4*)(orow + o) = ov;
            ushort4 hv = { f2bf(ov.x), f2bf(ov.y), f2bf(ov.z), f2bf(ov.w) };
            *(ushort4*)(orow16 + o) = hv;
        }
    }
}

// ---------------- edge preprocessing: deg (by src, no self-loops) + CSR by dst ----------------

__global__ void k_edges(const int* __restrict__ ei, int E, int* deg, int* cnt) {
    int e = blockIdx.x * blockDim.x + threadIdx.x;
    if (e >= E) return;
    int s = ei[e], d = ei[E + e];
    if (s != d) atomicAdd(&deg[s], 1);
    atomicAdd(&cnt[d], 1);
}

// hierarchical exclusive scan of cnt -> rowptr (3 small parallel kernels)
__global__ __launch_bounds__(1024) void k_scanA(const int* __restrict__ cnt,
                                                int* rowptr, int* bsum, int N) {
    __shared__ int buf[1024];
    int tid = threadIdx.x;
    int g = blockIdx.x * 1024 + tid;
    int v = (g < N) ? cnt[g] : 0;
    buf[tid] = v;
    __syncthreads();
    for (int off = 1; off < 1024; off <<= 1) {
        int t = (tid >= off) ? buf[tid - off] : 0;
        __syncthreads();
        buf[tid] += t;
        __syncthreads();
    }
    if (g < N) rowptr[g] = buf[tid] - v;          // exclusive within block
    if (tid == 1023) bsum[blockIdx.x] = buf[tid]; // block total
}

__global__ void k_scanB(int* bsum, int nb) {      // 1 block, 64 threads, nb<=64
    int lane = threadIdx.x & 63;
    int v = (lane < nb) ? bsum[lane] : 0;
    int orig = v;
#pragma unroll
    for (int off = 1; off < 64; off <<= 1) {
        int u = __shfl_up(v, off, 64);
        if (lane >= off) v += u;
    }
    if (lane < nb) bsum[lane] = v - orig;          // exclusive
}

__global__ __launch_bounds__(1024) void k_scanC(int* rowptr, const int* __restrict__ bsum,
                                                int* cursor, int N, int E) {
    int g = blockIdx.x * 1024 + threadIdx.x;
    if (g < N) {
        int v = rowptr[g] + bsum[g >> 10];
        rowptr[g] = v;
        cursor[g] = v;
    }
    if (g == 0) rowptr[N] = E;
}

__global__ void k_scatter(const int* __restrict__ ei, int E, int* cursor, int* colsrc) {
    int e = blockIdx.x * blockDim.x + threadIdx.x;
    if (e >= E) return;
    int s = ei[e], d = ei[E + e];
    int pos = atomicAdd(&cursor[d], 1);
    colsrc[pos] = s;
}

// canonicalize bucket order (determinism) + dinv — one WAVE per node.
__global__ __launch_bounds__(256) void k_sortdinv(
    const int* __restrict__ rowptr, int* colsrc,
    const int* __restrict__ deg, float* dinv, int N)
{
    int wid = (blockIdx.x * 256 + threadIdx.x) >> 6;
    int lane = threadIdx.x & 63;
    if (wid >= N) return;
    int b0 = rowptr[wid], b1 = rowptr[wid + 1];
    int d = b1 - b0;
    if (d > 1) {
        if (d <= 64) {
            int val = (lane < d) ? colsrc[b0 + lane] : INT_MAX;
#pragma unroll
            for (int k = 2; k <= 64; k <<= 1) {
#pragma unroll
                for (int j = k >> 1; j > 0; j >>= 1) {
                    int other = __shfl_xor(val, j, 64);
                    bool asc = ((lane & k) == 0);
                    bool lower = ((lane & j) == 0);
                    bool keepMin = (asc == lower);
                    val = keepMin ? min(val, other) : max(val, other);
                }
            }
            if (lane < d) colsrc[b0 + lane] = val;
        } else if (lane == 0) {
            for (int i = b0 + 1; i < b1; ++i) {
                int v = colsrc[i];
                int j = i - 1;
                while (j >= b0 && colsrc[j] > v) { colsrc[j + 1] = colsrc[j]; --j; }
                colsrc[j + 1] = v;
            }
        }
    }
    if (lane == 0) {
        int dg = deg[wid];
        dinv[wid] = dg > 0 ? 1.0f / sqrtf((float)dg) : 0.0f;
    }
}

// ---------------- pass 1: NodeInformationScore + sum_neigh (one fused gather) ----------------
// fp32 path — bit-identical score accumulation (sel decisions depend on it).

__global__ __launch_bounds__(256) void k_pass1(
    const float* __restrict__ utx, const int* __restrict__ rowptr,
    const int* __restrict__ colsrc, const float* __restrict__ dinv,
    float* __restrict__ score, float* __restrict__ sumn, int N)
{
    int wid = (blockIdx.x * 256 + threadIdx.x) >> 6;
    int lane = threadIdx.x & 63;
    if (wid >= N) return;
    float dn = dinv[wid];
    int b0 = rowptr[wid], b1 = rowptr[wid + 1];
    float accn = 0.f, accs = 0.f;
    for (int e0 = b0; e0 < b1; e0 += 8) {
        int sv_l = 0; float wv_l = 0.f, wn_l = 0.f;
        if (lane < 8) {
            int e  = e0 + lane;
            int ec = e < b1 ? e : (b1 - 1);
            int cs = colsrc[ec];
            sv_l = cs;
            bool ok = e < b1;
            wn_l = ok ? 1.0f : 0.0f;
            wv_l = (ok && cs != wid) ? dn * dinv[cs] : 0.0f;   // self-loop w=0
        }
#pragma unroll
        for (int i = 0; i < 8; ++i) {
            int   s = __builtin_amdgcn_readlane(sv_l, i);
            float w = rdlane_f(wv_l, i);
            float n = rdlane_f(wn_l, i);
            float v = utx[(size_t)s * 64 + lane];
            accn += w * v;
            accs += n * v;
        }
    }
    float info = utx[(size_t)wid * 64 + lane] - accn;
    float sc = wredsum(fabsf(info));
    sumn[(size_t)wid * 64 + lane] = accs;
    if (lane == 0) score[wid] = sc;
}

// ---------------- exact k-th largest via 2-pass radix histogram on float bits ----------------
// Wave-aggregated atomics: scores cluster into few hi-16 bins, so plain
// per-thread atomicAdd serializes ~50000 ops on a handful of addresses
// (round-6: k_hist1 70 us at 0.01% VALUBusy). One atomic per distinct
// bin per wave instead.

__device__ __forceinline__ void agg_hist_add(unsigned* __restrict__ hist,
                                             int bin, bool active, int lane) {
    unsigned long long mask = __ballot(active);
    while (mask) {
        int leader = (int)__ffsll((unsigned long long)mask) - 1;
        int lbin = __builtin_amdgcn_readlane(bin, leader);
        unsigned long long smask = __ballot(active && (bin == lbin));
        if (lane == leader) atomicAdd(&hist[lbin], (unsigned)__popcll(smask));
        mask &= ~smask;
    }
}

__global__ void k_hist1(const float* __restrict__ score, unsigned* histA, int N) {
    int n = blockIdx.x * blockDim.x + threadIdx.x;
    int lane = threadIdx.x & 63;
    bool active = n < N;
    unsigned bits = active ? __float_as_uint(score[n]) : 0u;  // score>=0 -> bit order == float order
    agg_hist_add(histA, (int)(bits >> 16), active, lane);
}

__global__ void k_hist2(const float* __restrict__ score, unsigned* histB,
                        const unsigned* __restrict__ scal, int N) {
    int n = blockIdx.x * blockDim.x + threadIdx.x;
    int lane = threadIdx.x & 63;
    unsigned hi = scal[0];
    bool active = false; unsigned bits = 0u;
    if (n < N) {
        bits = __float_as_uint(score[n]);
        active = (bits >> 16) == hi;
    }
    agg_hist_add(histB, (int)(bits & 0xFFFFu), active, lane);
}

// phase 1: find hi-16 bin of the K-th largest + residual rank; phase 2: lo-16 -> T bits.
// scal[0] holds the FULL hi-16 bin value — k_hist2 compares it against
// (bits >> 16) directly, and scal[2] = (hi16 << 16) | lo16. Read-only on hist
// (separate buffers, re-memset each launch).
__global__ __launch_bounds__(256) void k_pick(const unsigned* __restrict__ hist,
                                              unsigned* scal, int K, int phase) {
    __shared__ unsigned seg[256];
    int t = threadIdx.x;
    unsigned s = 0;
    for (int i = 0; i < 256; ++i) s += hist[t * 256 + i];
    seg[t] = s;
    __syncthreads();
    if (t == 0) {
        unsigned R = (phase == 1) ? (unsigned)K : scal[1];
        unsigned acc = 0;
        int S = 0;
        for (int si = 255; si >= 0; --si) {
            if (acc + seg[si] >= R) { S = si; break; }
            acc += seg[si];
        }
        int B = S * 256;
        for (int bin = S * 256 + 255; bin >= S * 256; --bin) {
            unsigned h = hist[bin];
            if (acc + h >= R) { B = bin; break; }
            acc += h;
        }
        if (phase == 1) { scal[0] = (unsigned)B; scal[1] = R - acc; }
        else           { scal[2] = (scal[0] << 16) | (unsigned)B; }
    }
}

__global__ void k_sel(const float* __restrict__ score, const unsigned* __restrict__ scal,
                      float* sel, int N) {
    int n = blockIdx.x * blockDim.x + threadIdx.x;
    if (n >= N) return;
    float T = __uint_as_float(scal[2]);
    sel[n] = (score[n] > T) ? 1.0f : 0.0f;       // strict >, matches reference
}

// ---------------- sum_sel via correction: sums = sumn - sum_{sel==0} utx ----------------
// ~25% of sources unselected; wave-uniform skip; bf16 gather (halves lines).

__global__ __launch_bounds__(256) void k_sums_corr(
    const unsigned short* __restrict__ utx16, const int* __restrict__ rowptr,
    const int* __restrict__ colsrc, const float* __restrict__ sel,
    const float* __restrict__ sumn, float* __restrict__ sums, int N)
{
    int wid = (blockIdx.x * 256 + threadIdx.x) >> 6;
    int lane = threadIdx.x & 63;
    if (wid >= N) return;
    int b0 = rowptr[wid], b1 = rowptr[wid + 1];
    float corr = 0.f;
    for (int e0 = b0; e0 < b1; e0 += 8) {
        int sv_l = 0; float w_l = 0.f;
        if (lane < 8) {
            int e  = e0 + lane;
            int ec = e < b1 ? e : (b1 - 1);
            int cs = colsrc[ec];
            sv_l = cs;
            w_l = (e < b1) ? (1.0f - sel[cs]) : 0.0f;   // 1 when NOT selected
        }
#pragma unroll
        for (int i = 0; i < 8; ++i) {
            float w = rdlane_f(w_l, i);
            int   s = __builtin_amdgcn_readlane(sv_l, i);
            if (w != 0.f)                                // wave-uniform branch
                corr += bf2f(utx16[(size_t)s * 64 + lane]);
        }
    }
    size_t o = (size_t)wid * 64 + lane;
    sums[o] = sumn[o] - corr;
}

// ---------------- wsel = sel * sigmoid(logmap0(hyp_linear(hyp_sums, beta_W, beta_b))) ----------------

__global__ __launch_bounds__(256) void k_beta(
    const float* __restrict__ sumn, const float* __restrict__ sums,
    const float* __restrict__ beta_W, const float* __restrict__ beta_b,
    const float* __restrict__ sel, float* __restrict__ wsel, int N)
{
    int wid = (blockIdx.x * 256 + threadIdx.x) >> 6;
    int lane = threadIdx.x & 63;
    if (wid >= N) return;
    // concat = [sum_sel, sum_neigh] (128 dims; lane holds dims lane and lane+64)
    float u0 = sums[(size_t)wid * 64 + lane];
    float u1 = sumn[(size_t)wid * 64 + lane];
    // hyp_sums = proj(expmap0(concat))
    float un = fmaxf(sqrtf(wredsum(u0 * u0 + u1 * u1)), MINNORM);
    float f = tanhf(un) / un;
    float h0 = f * u0, h1 = f * u1;
    float hn = fmaxf(sqrtf(wredsum(h0 * h0 + h1 * h1)), MINNORM);
    if (hn > MAXNORM) { float sc = MAXNORM / hn; h0 *= sc; h1 *= sc; }
    // mobius_matvec(beta_W [1,128], h) -> scalar
    float xn = fmaxf(sqrtf(wredsum(h0 * h0 + h1 * h1)), MINNORM);
    float mx = wredsum(h0 * beta_W[lane] + h1 * beta_W[64 + lane]);
    float mxn = fmaxf(fabsf(mx), MINNORM);
    float res = tanhf(mxn / xn * artanh_pos(xn)) * mx / mxn;
    float rn = fmaxf(fabsf(res), MINNORM);
    if (rn > MAXNORM) res = res / rn * MAXNORM;
    // hb = proj(expmap0(beta_b)) (scalar)
    float bb = beta_b[0];
    float bn = fmaxf(fabsf(bb), MINNORM);
    float hb = tanhf(bn) / bn * bb;
    float hbn = fmaxf(fabsf(hb), MINNORM);
    if (hbn > MAXNORM) hb = hb / hbn * MAXNORM;
    // mobius_add (1-dim)
    float x2 = res * res, y2 = hb * hb, xy = res * hb;
    float num = (1.f + 2.f * xy + y2) * res + (1.f - x2) * hb;
    float den = 1.f + 2.f * xy + x2 * y2;
    float p = num / fmaxf(den, MINNORM);
    float pn = fmaxf(fabsf(p), MINNORM);
    if (pn > MAXNORM) p = p / pn * MAXNORM;
    // logmap0 (1-dim) + sigmoid, pre-multiplied by sel gate
    float qn = fmaxf(fabsf(p), MINNORM);
    float lg = artanh_pos(qn) * p / qn;
    float w = 1.f / (1.f + expf(-lg));
    if (lane == 0) wsel[wid] = w * sel[wid];
}

// ---------------- A_x gather (bf16, lane-trick) + relu + expmap0/proj ----------------

__global__ __launch_bounds__(256) void k_axout(
    const float* __restrict__ utx, const unsigned short* __restrict__ utx16,
    const int* __restrict__ rowptr, const int* __restrict__ colsrc,
    const float* __restrict__ wsel, float* __restrict__ out, int N)
{
    int wid = (blockIdx.x * 256 + threadIdx.x) >> 6;
    int lane = threadIdx.x & 63;
    if (wid >= N) return;
    int b0 = rowptr[wid], b1 = rowptr[wid + 1];
    float acc = 0.f;
    for (int e0 = b0; e0 < b1; e0 += 8) {
        int sv_l = 0; float w_l = 0.f;
        if (lane < 8) {
            int e  = e0 + lane;
            int ec = e < b1 ? e : (b1 - 1);
            int cs = colsrc[ec];
            sv_l = cs;
            w_l = (e < b1) ? wsel[cs] : 0.0f;    // wsel already includes sel gate
        }
#pragma unroll
        for (int i = 0; i < 8; ++i) {
            int   s = __builtin_amdgcn_readlane(sv_l, i);
            float w = rdlane_f(w_l, i);
            acc += w * bf2f(utx16[(size_t)s * 64 + lane]);
        }
    }
    float a = fmaxf(acc, 0.f);                               // relu AFTER aggregation
    float u = utx[(size_t)wid * 64 + lane] + a;              // own row stays fp32
    float un = fmaxf(sqrtf(wredsum(u * u)), MINNORM);
    float o = tanhf(un) / un * u;                            // expmap0
    float on = fmaxf(sqrtf(wredsum(o * o)), MINNORM);
    if (on > MAXNORM) o *= MAXNORM / on;                     // proj
    out[(size_t)wid * 64 + lane] = o;
}

// ---------------- launch ----------------

extern "C" void kernel_launch(void* const* d_in, const int* in_sizes, int n_in,
                              void* d_out, int out_size, void* d_ws, size_t ws_size,
                              hipStream_t stream)
{
    const float* x      = (const float*)d_in[0];
    const float* W      = (const float*)d_in[1];
    const float* b      = (const float*)d_in[2];
    const float* beta_W = (const float*)d_in[3];
    const float* beta_b = (const float*)d_in[4];
    const int*   ei     = (const int*)d_in[5];

    const int N = in_sizes[0] / 128;
    const int E = in_sizes[5] / 2;
    const int K = (int)((double)N * 0.75);
    float* out = (float*)d_out;

    char* ws = (char*)d_ws;
    size_t off = 0;
    auto alloc = [&](size_t bytes) -> void* {
        void* p = ws + off;
        off = (off + bytes + 255) & ~(size_t)255;
        return p;
    };
    float*          utx    = (float*)alloc((size_t)N * 64 * 4);
    unsigned short* utx16  = (unsigned short*)alloc((size_t)N * 64 * 2);
    float*          sumn   = (float*)alloc((size_t)N * 64 * 4);
    float*          sums   = (float*)alloc((size_t)N * 64 * 4);
    float*          score  = (float*)alloc((size_t)N * 4);
    float*          dinv   = (float*)alloc((size_t)N * 4);
    float*          sel    = (float*)alloc((size_t)N * 4);
    float*          wsel   = (float*)alloc((size_t)N * 4);
    int*            deg    = (int*)alloc((size_t)N * 4);
    int*            cnt    = (int*)alloc((size_t)N * 4);
    int*            rowptr = (int*)alloc((size_t)(N + 1) * 4);
    int*            cursor = (int*)alloc((size_t)N * 4);
    int*            colsrc = (int*)alloc((size_t)E * 4);
    unsigned*       histA  = (unsigned*)alloc(65536 * 4);
    unsigned*       histB  = (unsigned*)alloc(65536 * 4);
    unsigned*       scal   = (unsigned*)alloc(64);
    int*            bsum   = (int*)alloc(256);
    if (off > ws_size) return;  // workspace too small (should not happen)

    hipMemsetAsync(deg,   0, (size_t)N * 4, stream);
    hipMemsetAsync(cnt,   0, (size_t)N * 4, stream);
    hipMemsetAsync(histA, 0, 65536 * 4 * 2, stream);   // histA + histB contiguous

    int gE  = (E + 255) / 256;
    int gN  = (N + 255) / 256;
    int gNb = (N + 1023) / 1024;     // scan blocks (<=64 for N<=65536)
    int gW  = (N + 3) / 4;           // wave-per-node kernels
    int gLin = (N + 63) / 64;        // k_linear: one 64-row tile per block, 4 K-split waves

    k_linear<<<gLin, 256, 0, stream>>>(x, W, b, utx, utx16, N);
    k_edges<<<gE, 256, 0, stream>>>(ei, E, deg, cnt);
    k_scanA<<<gNb, 1024, 0, stream>>>(cnt, rowptr, bsum, N);
    k_scanB<<<1, 64, 0, stream>>>(bsum, gNb);
    k_scanC<<<gNb, 1024, 0, stream>>>(rowptr, bsum, cursor, N, E);
    k_scatter<<<gE, 256, 0, stream>>>(ei, E, cursor, colsrc);
    k_sortdinv<<<gW, 256, 0, stream>>>(rowptr, colsrc, deg, dinv, N);
    k_pass1<<<gW, 256, 0, stream>>>(utx, rowptr, colsrc, dinv, score, sumn, N);
    k_hist1<<<gN, 256, 0, stream>>>(score, histA, N);
    k_pick<<<1, 256, 0, stream>>>(histA, scal, K, 1);
    k_hist2<<<gN, 256, 0, stream>>>(score, histB, scal, N);
    k_pick<<<1, 256, 0, stream>>>(histB, scal, K, 2);
    k_sel<<<gN, 256, 0, stream>>>(score, scal, sel, N);
    k_sums_corr<<<gW, 256, 0, stream>>>(utx16, rowptr, colsrc, sel, sumn, sums, N);
    k_beta<<<gW, 256, 0, stream>>>(sumn, sums, beta_W, beta_b, sel, wsel, N);
    k_axout<<<gW, 256, 0, stream>>>(utx, utx16, rowptr, colsrc, wsel, out, N);
}

// Round 8
// 417.530 us; speedup vs baseline: 1.3245x; 1.3245x over previous
//
#include <hip/hip_runtime.h>
#include <math.h>
#include <limits.h>

// ---------------- helpers ----------------

__device__ __forceinline__ float wredsum(float v) {
#pragma unroll
    for (int off = 32; off > 0; off >>= 1) v += __shfl_xor(v, off, 64);
    return v;
}

__device__ __forceinline__ float rdlane_f(float v, int i) {
    return __uint_as_float(__builtin_amdgcn_readlane(__float_as_uint(v), i));
}

// artanh for z >= 0, clipped like the reference (1 - 1e-7), accurate for tiny z
__device__ __forceinline__ float artanh_pos(float z) {
    z = fminf(z, 1.0f - 1e-7f);
    return 0.5f * (log1pf(z) - log1pf(-z));
}

// fp32 <-> bf16 (round-to-nearest-even)
__device__ __forceinline__ unsigned short f2bf(float f) {
    unsigned u = __float_as_uint(f);
    unsigned r = 0x7FFFu + ((u >> 16) & 1u);
    return (unsigned short)((u + r) >> 16);
}
__device__ __forceinline__ float bf2f(unsigned short h) {
    return __uint_as_float(((unsigned)h) << 16);
}

#define MAXNORM 0.996f   // (1 - 4e-3)/sqrt(c), c = 1
#define MINNORM 1e-15f

// ---------------- kernel 1: utx = logmap0(hyp_linear(x,W,b)) ----------------
// lane = row, 64 rows per BLOCK; the block's 4 waves split K (32 floats each)
// and reduce partial acc[64] + xsq through LDS into wave 0, which runs the
// epilogue. W reads stay wave-uniform (readfirstlane-pinned) -> s_load path.
// Writes fp32 utx (score path, bit-exact) AND bf16 utx16 (bulk gather paths).

__global__ __launch_bounds__(256) void k_linear(
    const float* __restrict__ x, const float* __restrict__ Wg,
    const float* __restrict__ b, float* __restrict__ utx,
    unsigned short* __restrict__ utx16, int N)
{
    __shared__ float hb_s[64];
    __shared__ float red[3][16][64];   // 12 KB: 16-reg chunks, lane-contiguous (conflict-free)
    __shared__ float xq_s[3][64];
    int tid = threadIdx.x;
    int wave = tid >> 6, lane = tid & 63;
    int wave_u = __builtin_amdgcn_readfirstlane(wave);  // keep W addressing scalar

    if (wave == 0) {
        // hb = proj(expmap0(b)) : 64-dim (lane = dim)
        float bv = b[lane];
        float bn = fmaxf(sqrtf(wredsum(bv * bv)), MINNORM);
        float h = tanhf(bn) / bn * bv;
        float hn = fmaxf(sqrtf(wredsum(h * h)), MINNORM);
        if (hn > MAXNORM) h *= MAXNORM / hn;
        hb_s[lane] = h;
    }
    __syncthreads();

    int row = blockIdx.x * 64 + lane;
    bool valid = row < N;
    int srow = valid ? row : (N - 1);
    const float* xr = x + (size_t)srow * 128 + wave_u * 32;
    const float* wr = Wg + wave_u * 32;

    float acc[64];
#pragma unroll
    for (int o = 0; o < 64; ++o) acc[o] = 0.f;
    float xsq = 0.f;

    for (int jt = 0; jt < 8; ++jt) {             // this wave's quarter of K
        float4 xv = *(const float4*)(xr + jt * 4);
        xsq += xv.x * xv.x + xv.y * xv.y + xv.z * xv.z + xv.w * xv.w;
#pragma unroll
        for (int o = 0; o < 64; ++o) {           // wave-uniform -> s_load
            float4 wv = *(const float4*)(wr + o * 128 + jt * 4);
            acc[o] += xv.x * wv.x + xv.y * wv.y + xv.z * wv.z + xv.w * wv.w;
        }
    }

    // ---- cross-wave reduction (fixed order -> deterministic) ----
    if (wave_u != 0) xq_s[wave_u - 1][lane] = xsq;
#pragma unroll
    for (int c = 0; c < 4; ++c) {
        if (wave_u != 0) {
#pragma unroll
            for (int r = 0; r < 16; ++r) red[wave_u - 1][r][lane] = acc[c * 16 + r];
        }
        __syncthreads();
        if (wave_u == 0) {
#pragma unroll
            for (int r = 0; r < 16; ++r)
                acc[c * 16 + r] += red[0][r][lane] + red[1][r][lane] + red[2][r][lane];
        }
        __syncthreads();
    }
    if (wave_u != 0) return;                     // epilogue is wave 0 only
    xsq += xq_s[0][lane] + xq_s[1][lane] + xq_s[2][lane];

    // ---- epilogue, all per-lane scalar ----
    float mx2 = 0.f;
#pragma unroll
    for (int o = 0; o < 64; ++o) mx2 += acc[o] * acc[o];

    float xn  = fmaxf(sqrtf(xsq), MINNORM);
    float mxn = fmaxf(sqrtf(mx2), MINNORM);
    float fac = tanhf(mxn / xn * artanh_pos(xn)) / mxn;   // mobius_matvec scale
    float rn  = fac * mxn;                                // ||res||
    if (rn > MAXNORM) { fac *= MAXNORM / rn; rn = MAXNORM; }  // proj
    float x2 = rn * rn;

    // hb2 = ||hb||^2 (wave-uniform)
    float hv_ = hb_s[lane];
    float hb2 = wredsum(hv_ * hv_);

    // mobius_add(res, hb): xy = <res, hb>
    float xy = 0.f;
#pragma unroll
    for (int o = 0; o < 64; ++o) xy += (fac * acc[o]) * hb_s[o];

    float den = fmaxf(1.f + 2.f * xy + x2 * hb2, MINNORM);
    float ca  = (1.f + 2.f * xy + hb2) / den;   // coeff on res
    float cb  = (1.f - x2) / den;               // coeff on hb

    float pn2 = 0.f;
#pragma unroll
    for (int o = 0; o < 64; ++o) {
        float p = ca * (fac * acc[o]) + cb * hb_s[o];
        acc[o] = p;
        pn2 += p * p;
    }
    float pn  = fmaxf(sqrtf(pn2), MINNORM);
    float psc = (pn > MAXNORM) ? (MAXNORM / pn) : 1.0f;   // proj
    float qn  = fmaxf(pn * psc, MINNORM);
    float lfac = artanh_pos(qn) / qn * psc;               // logmap0 scale

    if (valid) {
        float* orow = utx + (size_t)row * 64;
        unsigned short* orow16 = utx16 + (size_t)row * 64;
#pragma unroll
        for (int o = 0; o < 64; o += 4) {
            float4 ov = { acc[o] * lfac, acc[o + 1] * lfac,
                          acc[o + 2] * lfac, acc[o + 3] * lfac };
            *(float4*)(orow + o) = ov;
            ushort4 hv = { f2bf(ov.x), f2bf(ov.y), f2bf(ov.z), f2bf(ov.w) };
            *(ushort4*)(orow16 + o) = hv;
        }
    }
}

// ---------------- edge preprocessing: deg (by src, no self-loops) + CSR by dst ----------------

__global__ void k_edges(const int* __restrict__ ei, int E, int* deg, int* cnt) {
    int e = blockIdx.x * blockDim.x + threadIdx.x;
    if (e >= E) return;
    int s = ei[e], d = ei[E + e];
    if (s != d) atomicAdd(&deg[s], 1);
    atomicAdd(&cnt[d], 1);
}

// hierarchical exclusive scan of cnt -> rowptr (3 small parallel kernels)
__global__ __launch_bounds__(1024) void k_scanA(const int* __restrict__ cnt,
                                                int* rowptr, int* bsum, int N) {
    __shared__ int buf[1024];
    int tid = threadIdx.x;
    int g = blockIdx.x * 1024 + tid;
    int v = (g < N) ? cnt[g] : 0;
    buf[tid] = v;
    __syncthreads();
    for (int off = 1; off < 1024; off <<= 1) {
        int t = (tid >= off) ? buf[tid - off] : 0;
        __syncthreads();
        buf[tid] += t;
        __syncthreads();
    }
    if (g < N) rowptr[g] = buf[tid] - v;          // exclusive within block
    if (tid == 1023) bsum[blockIdx.x] = buf[tid]; // block total
}

__global__ void k_scanB(int* bsum, int nb) {      // 1 block, 64 threads, nb<=64
    int lane = threadIdx.x & 63;
    int v = (lane < nb) ? bsum[lane] : 0;
    int orig = v;
#pragma unroll
    for (int off = 1; off < 64; off <<= 1) {
        int u = __shfl_up(v, off, 64);
        if (lane >= off) v += u;
    }
    if (lane < nb) bsum[lane] = v - orig;          // exclusive
}

__global__ __launch_bounds__(1024) void k_scanC(int* rowptr, const int* __restrict__ bsum,
                                                int* cursor, int N, int E) {
    int g = blockIdx.x * 1024 + threadIdx.x;
    if (g < N) {
        int v = rowptr[g] + bsum[g >> 10];
        rowptr[g] = v;
        cursor[g] = v;
    }
    if (g == 0) rowptr[N] = E;
}

__global__ void k_scatter(const int* __restrict__ ei, int E, int* cursor, int* colsrc) {
    int e = blockIdx.x * blockDim.x + threadIdx.x;
    if (e >= E) return;
    int s = ei[e], d = ei[E + e];
    int pos = atomicAdd(&cursor[d], 1);
    colsrc[pos] = s;
}

// canonicalize bucket order (determinism) + dinv — one WAVE per node.
__global__ __launch_bounds__(256) void k_sortdinv(
    const int* __restrict__ rowptr, int* colsrc,
    const int* __restrict__ deg, float* dinv, int N)
{
    int wid = (blockIdx.x * 256 + threadIdx.x) >> 6;
    int lane = threadIdx.x & 63;
    if (wid >= N) return;
    int b0 = rowptr[wid], b1 = rowptr[wid + 1];
    int d = b1 - b0;
    if (d > 1) {
        if (d <= 64) {
            int val = (lane < d) ? colsrc[b0 + lane] : INT_MAX;
#pragma unroll
            for (int k = 2; k <= 64; k <<= 1) {
#pragma unroll
                for (int j = k >> 1; j > 0; j >>= 1) {
                    int other = __shfl_xor(val, j, 64);
                    bool asc = ((lane & k) == 0);
                    bool lower = ((lane & j) == 0);
                    bool keepMin = (asc == lower);
                    val = keepMin ? min(val, other) : max(val, other);
                }
            }
            if (lane < d) colsrc[b0 + lane] = val;
        } else if (lane == 0) {
            for (int i = b0 + 1; i < b1; ++i) {
                int v = colsrc[i];
                int j = i - 1;
                while (j >= b0 && colsrc[j] > v) { colsrc[j + 1] = colsrc[j]; --j; }
                colsrc[j + 1] = v;
            }
        }
    }
    if (lane == 0) {
        int dg = deg[wid];
        dinv[wid] = dg > 0 ? 1.0f / sqrtf((float)dg) : 0.0f;
    }
}

// ---------------- pass 1: NodeInformationScore + sum_neigh (one fused gather) ----------------
// fp32 path — bit-identical score accumulation (sel decisions depend on it).

__global__ __launch_bounds__(256) void k_pass1(
    const float* __restrict__ utx, const int* __restrict__ rowptr,
    const int* __restrict__ colsrc, const float* __restrict__ dinv,
    float* __restrict__ score, float* __restrict__ sumn, int N)
{
    int wid = (blockIdx.x * 256 + threadIdx.x) >> 6;
    int lane = threadIdx.x & 63;
    if (wid >= N) return;
    float dn = dinv[wid];
    int b0 = rowptr[wid], b1 = rowptr[wid + 1];
    float accn = 0.f, accs = 0.f;
    for (int e0 = b0; e0 < b1; e0 += 8) {
        int sv_l = 0; float wv_l = 0.f, wn_l = 0.f;
        if (lane < 8) {
            int e  = e0 + lane;
            int ec = e < b1 ? e : (b1 - 1);
            int cs = colsrc[ec];
            sv_l = cs;
            bool ok = e < b1;
            wn_l = ok ? 1.0f : 0.0f;
            wv_l = (ok && cs != wid) ? dn * dinv[cs] : 0.0f;   // self-loop w=0
        }
#pragma unroll
        for (int i = 0; i < 8; ++i) {
            int   s = __builtin_amdgcn_readlane(sv_l, i);
            float w = rdlane_f(wv_l, i);
            float n = rdlane_f(wn_l, i);
            float v = utx[(size_t)s * 64 + lane];
            accn += w * v;
            accs += n * v;
        }
    }
    float info = utx[(size_t)wid * 64 + lane] - accn;
    float sc = wredsum(fabsf(info));
    sumn[(size_t)wid * 64 + lane] = accs;
    if (lane == 0) score[wid] = sc;
}

// ---------------- exact k-th largest via 4-pass 8-bit radix select ----------------
// Round-7 lesson: scores spread over ~200 distinct hi-16 bins, so both plain
// and wave-aggregated global atomics serialize. LDS-privatized 256-bin
// histograms cut global atomic traffic ~200x; k-th-largest bit pattern is
// recovered exactly over 4 byte passes (scal[2] = exact T bits, same T as
// before -> sel set unchanged).

__global__ __launch_bounds__(256) void k_hist8(
    const float* __restrict__ score, unsigned* __restrict__ hist,
    const unsigned* __restrict__ scal, int N, int pass)
{
    __shared__ unsigned lh[256];
    int tid = threadIdx.x;
    lh[tid] = 0;
    __syncthreads();
    int n = blockIdx.x * 256 + tid;
    if (n < N) {
        unsigned bits = __float_as_uint(score[n]);   // score>=0 -> bit order == value order
        bool active = (pass == 0) || (((bits ^ scal[0]) >> (32 - 8 * pass)) == 0u);
        if (active) atomicAdd(&lh[(bits >> (24 - 8 * pass)) & 0xFFu], 1u);
    }
    __syncthreads();
    unsigned c = lh[tid];
    if (c) atomicAdd(&hist[tid], c);
}

__global__ __launch_bounds__(256) void k_pick8(
    const unsigned* __restrict__ hist, unsigned* scal, int K, int pass)
{
    __shared__ unsigned h[256];
    int t = threadIdx.x;
    h[t] = hist[t];
    __syncthreads();
    if (t == 0) {
        unsigned R = (pass == 0) ? (unsigned)K : scal[1];
        unsigned acc = 0;
        int B = 0;
        for (int bin = 255; bin >= 0; --bin) {       // descending: k-th LARGEST
            if (acc + h[bin] >= R) { B = bin; break; }
            acc += h[bin];
        }
        unsigned prefix = (pass == 0) ? 0u : scal[0];
        scal[0] = prefix | ((unsigned)B << (24 - 8 * pass));
        scal[1] = R - acc;
        if (pass == 3) scal[2] = scal[0];            // exact T bit pattern
    }
}

__global__ void k_sel(const float* __restrict__ score, const unsigned* __restrict__ scal,
                      float* sel, int N) {
    int n = blockIdx.x * blockDim.x + threadIdx.x;
    if (n >= N) return;
    float T = __uint_as_float(scal[2]);
    sel[n] = (score[n] > T) ? 1.0f : 0.0f;       // strict >, matches reference
}

// ---------------- sum_sel via correction: sums = sumn - sum_{sel==0} utx ----------------
// ~25% of sources unselected; wave-uniform skip; bf16 gather (halves lines).

__global__ __launch_bounds__(256) void k_sums_corr(
    const unsigned short* __restrict__ utx16, const int* __restrict__ rowptr,
    const int* __restrict__ colsrc, const float* __restrict__ sel,
    const float* __restrict__ sumn, float* __restrict__ sums, int N)
{
    int wid = (blockIdx.x * 256 + threadIdx.x) >> 6;
    int lane = threadIdx.x & 63;
    if (wid >= N) return;
    int b0 = rowptr[wid], b1 = rowptr[wid + 1];
    float corr = 0.f;
    for (int e0 = b0; e0 < b1; e0 += 8) {
        int sv_l = 0; float w_l = 0.f;
        if (lane < 8) {
            int e  = e0 + lane;
            int ec = e < b1 ? e : (b1 - 1);
            int cs = colsrc[ec];
            sv_l = cs;
            w_l = (e < b1) ? (1.0f - sel[cs]) : 0.0f;   // 1 when NOT selected
        }
#pragma unroll
        for (int i = 0; i < 8; ++i) {
            float w = rdlane_f(w_l, i);
            int   s = __builtin_amdgcn_readlane(sv_l, i);
            if (w != 0.f)                                // wave-uniform branch
                corr += bf2f(utx16[(size_t)s * 64 + lane]);
        }
    }
    size_t o = (size_t)wid * 64 + lane;
    sums[o] = sumn[o] - corr;
}

// ---------------- wsel = sel * sigmoid(logmap0(hyp_linear(hyp_sums, beta_W, beta_b))) ----------------

__global__ __launch_bounds__(256) void k_beta(
    const float* __restrict__ sumn, const float* __restrict__ sums,
    const float* __restrict__ beta_W, const float* __restrict__ beta_b,
    const float* __restrict__ sel, float* __restrict__ wsel, int N)
{
    int wid = (blockIdx.x * 256 + threadIdx.x) >> 6;
    int lane = threadIdx.x & 63;
    if (wid >= N) return;
    // concat = [sum_sel, sum_neigh] (128 dims; lane holds dims lane and lane+64)
    float u0 = sums[(size_t)wid * 64 + lane];
    float u1 = sumn[(size_t)wid * 64 + lane];
    // hyp_sums = proj(expmap0(concat))
    float un = fmaxf(sqrtf(wredsum(u0 * u0 + u1 * u1)), MINNORM);
    float f = tanhf(un) / un;
    float h0 = f * u0, h1 = f * u1;
    float hn = fmaxf(sqrtf(wredsum(h0 * h0 + h1 * h1)), MINNORM);
    if (hn > MAXNORM) { float sc = MAXNORM / hn; h0 *= sc; h1 *= sc; }
    // mobius_matvec(beta_W [1,128], h) -> scalar
    float xn = fmaxf(sqrtf(wredsum(h0 * h0 + h1 * h1)), MINNORM);
    float mx = wredsum(h0 * beta_W[lane] + h1 * beta_W[64 + lane]);
    float mxn = fmaxf(fabsf(mx), MINNORM);
    float res = tanhf(mxn / xn * artanh_pos(xn)) * mx / mxn;
    float rn = fmaxf(fabsf(res), MINNORM);
    if (rn > MAXNORM) res = res / rn * MAXNORM;
    // hb = proj(expmap0(beta_b)) (scalar)
    float bb = beta_b[0];
    float bn = fmaxf(fabsf(bb), MINNORM);
    float hb = tanhf(bn) / bn * bb;
    float hbn = fmaxf(fabsf(hb), MINNORM);
    if (hbn > MAXNORM) hb = hb / hbn * MAXNORM;
    // mobius_add (1-dim)
    float x2 = res * res, y2 = hb * hb, xy = res * hb;
    float num = (1.f + 2.f * xy + y2) * res + (1.f - x2) * hb;
    float den = 1.f + 2.f * xy + x2 * y2;
    float p = num / fmaxf(den, MINNORM);
    float pn = fmaxf(fabsf(p), MINNORM);
    if (pn > MAXNORM) p = p / pn * MAXNORM;
    // logmap0 (1-dim) + sigmoid, pre-multiplied by sel gate
    float qn = fmaxf(fabsf(p), MINNORM);
    float lg = artanh_pos(qn) * p / qn;
    float w = 1.f / (1.f + expf(-lg));
    if (lane == 0) wsel[wid] = w * sel[wid];
}

// ---------------- A_x gather (bf16, lane-trick) + relu + expmap0/proj ----------------

__global__ __launch_bounds__(256) void k_axout(
    const float* __restrict__ utx, const unsigned short* __restrict__ utx16,
    const int* __restrict__ rowptr, const int* __restrict__ colsrc,
    const float* __restrict__ wsel, float* __restrict__ out, int N)
{
    int wid = (blockIdx.x * 256 + threadIdx.x) >> 6;
    int lane = threadIdx.x & 63;
    if (wid >= N) return;
    int b0 = rowptr[wid], b1 = rowptr[wid + 1];
    float acc = 0.f;
    for (int e0 = b0; e0 < b1; e0 += 8) {
        int sv_l = 0; float w_l = 0.f;
        if (lane < 8) {
            int e  = e0 + lane;
            int ec = e < b1 ? e : (b1 - 1);
            int cs = colsrc[ec];
            sv_l = cs;
            w_l = (e < b1) ? wsel[cs] : 0.0f;    // wsel already includes sel gate
        }
#pragma unroll
        for (int i = 0; i < 8; ++i) {
            int   s = __builtin_amdgcn_readlane(sv_l, i);
            float w = rdlane_f(w_l, i);
            acc += w * bf2f(utx16[(size_t)s * 64 + lane]);
        }
    }
    float a = fmaxf(acc, 0.f);                               // relu AFTER aggregation
    float u = utx[(size_t)wid * 64 + lane] + a;              // own row stays fp32
    float un = fmaxf(sqrtf(wredsum(u * u)), MINNORM);
    float o = tanhf(un) / un * u;                            // expmap0
    float on = fmaxf(sqrtf(wredsum(o * o)), MINNORM);
    if (on > MAXNORM) o *= MAXNORM / on;                     // proj
    out[(size_t)wid * 64 + lane] = o;
}

// ---------------- launch ----------------

extern "C" void kernel_launch(void* const* d_in, const int* in_sizes, int n_in,
                              void* d_out, int out_size, void* d_ws, size_t ws_size,
                              hipStream_t stream)
{
    const float* x      = (const float*)d_in[0];
    const float* W      = (const float*)d_in[1];
    const float* b      = (const float*)d_in[2];
    const float* beta_W = (const float*)d_in[3];
    const float* beta_b = (const float*)d_in[4];
    const int*   ei     = (const int*)d_in[5];

    const int N = in_sizes[0] / 128;
    const int E = in_sizes[5] / 2;
    const int K = (int)((double)N * 0.75);
    float* out = (float*)d_out;

    char* ws = (char*)d_ws;
    size_t off = 0;
    auto alloc = [&](size_t bytes) -> void* {
        void* p = ws + off;
        off = (off + bytes + 255) & ~(size_t)255;
        return p;
    };
    float*          utx    = (float*)alloc((size_t)N * 64 * 4);
    unsigned short* utx16  = (unsigned short*)alloc((size_t)N * 64 * 2);
    float*          sumn   = (float*)alloc((size_t)N * 64 * 4);
    float*          sums   = (float*)alloc((size_t)N * 64 * 4);
    float*          score  = (float*)alloc((size_t)N * 4);
    float*          dinv   = (float*)alloc((size_t)N * 4);
    float*          sel    = (float*)alloc((size_t)N * 4);
    float*          wsel   = (float*)alloc((size_t)N * 4);
    int*            deg    = (int*)alloc((size_t)N * 4);
    int*            cnt    = (int*)alloc((size_t)N * 4);
    int*            rowptr = (int*)alloc((size_t)(N + 1) * 4);
    int*            cursor = (int*)alloc((size_t)N * 4);
    int*            colsrc = (int*)alloc((size_t)E * 4);
    unsigned*       hist8  = (unsigned*)alloc(4 * 256 * 4);   // 4 passes x 256 bins
    unsigned*       scal   = (unsigned*)alloc(64);
    int*            bsum   = (int*)alloc(256);
    if (off > ws_size) return;  // workspace too small (should not happen)

    hipMemsetAsync(deg,   0, (size_t)N * 4, stream);
    hipMemsetAsync(cnt,   0, (size_t)N * 4, stream);
    hipMemsetAsync(hist8, 0, 4 * 256 * 4, stream);

    int gE  = (E + 255) / 256;
    int gN  = (N + 255) / 256;
    int gNb = (N + 1023) / 1024;     // scan blocks (<=64 for N<=65536)
    int gW  = (N + 3) / 4;           // wave-per-node kernels
    int gLin = (N + 63) / 64;        // k_linear: one 64-row tile per block, 4 K-split waves

    k_linear<<<gLin, 256, 0, stream>>>(x, W, b, utx, utx16, N);
    k_edges<<<gE, 256, 0, stream>>>(ei, E, deg, cnt);
    k_scanA<<<gNb, 1024, 0, stream>>>(cnt, rowptr, bsum, N);
    k_scanB<<<1, 64, 0, stream>>>(bsum, gNb);
    k_scanC<<<gNb, 1024, 0, stream>>>(rowptr, bsum, cursor, N, E);
    k_scatter<<<gE, 256, 0, stream>>>(ei, E, cursor, colsrc);
    k_sortdinv<<<gW, 256, 0, stream>>>(rowptr, colsrc, deg, dinv, N);
    k_pass1<<<gW, 256, 0, stream>>>(utx, rowptr, colsrc, dinv, score, sumn, N);
    for (int pass = 0; pass < 4; ++pass) {
        k_hist8<<<gN, 256, 0, stream>>>(score, hist8 + 256 * pass, scal, N, pass);
        k_pick8<<<1, 256, 0, stream>>>(hist8 + 256 * pass, scal, K, pass);
    }
    k_sel<<<gN, 256, 0, stream>>>(score, scal, sel, N);
    k_sums_corr<<<gW, 256, 0, stream>>>(utx16, rowptr, colsrc, sel, sumn, sums, N);
    k_beta<<<gW, 256, 0, stream>>>(sumn, sums, beta_W, beta_b, sel, wsel, N);
    k_axout<<<gW, 256, 0, stream>>>(utx, utx16, rowptr, colsrc, wsel, out, N);
}

// Round 9
// 352.854 us; speedup vs baseline: 1.5673x; 1.1833x over previous
//
#include <hip/hip_runtime.h>
#include <math.h>
#include <limits.h>

// ---------------- helpers ----------------

__device__ __forceinline__ float wredsum(float v) {
#pragma unroll
    for (int off = 32; off > 0; off >>= 1) v += __shfl_xor(v, off, 64);
    return v;
}

__device__ __forceinline__ float rdlane_f(float v, int i) {
    return __uint_as_float(__builtin_amdgcn_readlane(__float_as_uint(v), i));
}

// artanh for z >= 0, clipped like the reference (1 - 1e-7), accurate for tiny z
__device__ __forceinline__ float artanh_pos(float z) {
    z = fminf(z, 1.0f - 1e-7f);
    return 0.5f * (log1pf(z) - log1pf(-z));
}

// fp32 <-> bf16 (round-to-nearest-even)
__device__ __forceinline__ unsigned short f2bf(float f) {
    unsigned u = __float_as_uint(f);
    unsigned r = 0x7FFFu + ((u >> 16) & 1u);
    return (unsigned short)((u + r) >> 16);
}
__device__ __forceinline__ float bf2f(unsigned short h) {
    return __uint_as_float(((unsigned)h) << 16);
}

#define MAXNORM 0.996f   // (1 - 4e-3)/sqrt(c), c = 1
#define MINNORM 1e-15f
#define SLOT    64       // per-node slot capacity; in-deg ~ Poisson(16), P(>=64) ~ e^-40

// ---------------- kernel 1: utx = logmap0(hyp_linear(x,W,b)) ----------------
// lane = row, 64 rows per BLOCK; 4 waves split K (32 floats each) and reduce
// through LDS into wave 0. W is staged in LDS once per block (32 KB); with
// lane=row every lane reads the SAME W address -> LDS broadcast (conflict-
// free), eliminating the s_load latency chain that capped round 8 at 70 us.

__global__ __launch_bounds__(256) void k_linear(
    const float* __restrict__ x, const float* __restrict__ Wg,
    const float* __restrict__ b, float* __restrict__ utx,
    unsigned short* __restrict__ utx16, int N)
{
    __shared__ float Ws[8192];         // 32 KB: W[64][128] row-major
    __shared__ float hb_s[64];
    __shared__ float red[3][16][64];   // 12 KB: 16-reg chunks, lane-contiguous
    __shared__ float xq_s[3][64];
    int tid = threadIdx.x;
    int wave = tid >> 6, lane = tid & 63;
    int wave_u = __builtin_amdgcn_readfirstlane(wave);

    {   // stage W: 2048 float4, coalesced
        const float4* Wg4 = (const float4*)Wg;
        float4* Ws4 = (float4*)Ws;
        for (int i = tid; i < 2048; i += 256) Ws4[i] = Wg4[i];
    }
    if (wave == 0) {
        // hb = proj(expmap0(b)) : 64-dim (lane = dim)
        float bv = b[lane];
        float bn = fmaxf(sqrtf(wredsum(bv * bv)), MINNORM);
        float h = tanhf(bn) / bn * bv;
        float hn = fmaxf(sqrtf(wredsum(h * h)), MINNORM);
        if (hn > MAXNORM) h *= MAXNORM / hn;
        hb_s[lane] = h;
    }
    __syncthreads();

    int row = blockIdx.x * 64 + lane;
    bool valid = row < N;
    int srow = valid ? row : (N - 1);
    const float* xr = x + (size_t)srow * 128 + wave_u * 32;
    const float* wr = Ws + wave_u * 32;          // LDS, uniform addr -> broadcast

    float acc[64];
#pragma unroll
    for (int o = 0; o < 64; ++o) acc[o] = 0.f;
    float xsq = 0.f;

    for (int jt = 0; jt < 8; ++jt) {             // this wave's quarter of K
        float4 xv = *(const float4*)(xr + jt * 4);
        xsq += xv.x * xv.x + xv.y * xv.y + xv.z * xv.z + xv.w * xv.w;
#pragma unroll
        for (int o = 0; o < 64; ++o) {
            float4 wv = *(const float4*)(wr + o * 128 + jt * 4);   // ds_read broadcast
            acc[o] += xv.x * wv.x + xv.y * wv.y + xv.z * wv.z + xv.w * wv.w;
        }
    }

    // ---- cross-wave reduction (fixed order -> deterministic) ----
    if (wave_u != 0) xq_s[wave_u - 1][lane] = xsq;
#pragma unroll
    for (int c = 0; c < 4; ++c) {
        if (wave_u != 0) {
#pragma unroll
            for (int r = 0; r < 16; ++r) red[wave_u - 1][r][lane] = acc[c * 16 + r];
        }
        __syncthreads();
        if (wave_u == 0) {
#pragma unroll
            for (int r = 0; r < 16; ++r)
                acc[c * 16 + r] += red[0][r][lane] + red[1][r][lane] + red[2][r][lane];
        }
        __syncthreads();
    }
    if (wave_u != 0) return;                     // epilogue is wave 0 only
    xsq += xq_s[0][lane] + xq_s[1][lane] + xq_s[2][lane];

    // ---- epilogue, all per-lane scalar ----
    float mx2 = 0.f;
#pragma unroll
    for (int o = 0; o < 64; ++o) mx2 += acc[o] * acc[o];

    float xn  = fmaxf(sqrtf(xsq), MINNORM);
    float mxn = fmaxf(sqrtf(mx2), MINNORM);
    float fac = tanhf(mxn / xn * artanh_pos(xn)) / mxn;   // mobius_matvec scale
    float rn  = fac * mxn;                                // ||res||
    if (rn > MAXNORM) { fac *= MAXNORM / rn; rn = MAXNORM; }  // proj
    float x2 = rn * rn;

    // hb2 = ||hb||^2 (wave-uniform)
    float hv_ = hb_s[lane];
    float hb2 = wredsum(hv_ * hv_);

    // mobius_add(res, hb): xy = <res, hb>
    float xy = 0.f;
#pragma unroll
    for (int o = 0; o < 64; ++o) xy += (fac * acc[o]) * hb_s[o];

    float den = fmaxf(1.f + 2.f * xy + x2 * hb2, MINNORM);
    float ca  = (1.f + 2.f * xy + hb2) / den;   // coeff on res
    float cb  = (1.f - x2) / den;               // coeff on hb

    float pn2 = 0.f;
#pragma unroll
    for (int o = 0; o < 64; ++o) {
        float p = ca * (fac * acc[o]) + cb * hb_s[o];
        acc[o] = p;
        pn2 += p * p;
    }
    float pn  = fmaxf(sqrtf(pn2), MINNORM);
    float psc = (pn > MAXNORM) ? (MAXNORM / pn) : 1.0f;   // proj
    float qn  = fmaxf(pn * psc, MINNORM);
    float lfac = artanh_pos(qn) / qn * psc;               // logmap0 scale

    if (valid) {
        float* orow = utx + (size_t)row * 64;
        unsigned short* orow16 = utx16 + (size_t)row * 64;
#pragma unroll
        for (int o = 0; o < 64; o += 4) {
            float4 ov = { acc[o] * lfac, acc[o + 1] * lfac,
                          acc[o + 2] * lfac, acc[o + 3] * lfac };
            *(float4*)(orow + o) = ov;
            ushort4 hv = { f2bf(ov.x), f2bf(ov.y), f2bf(ov.z), f2bf(ov.w) };
            *(ushort4*)(orow16 + o) = hv;
        }
    }
}

// ---------------- edge preprocessing: one fused pass -> slot-CSR ----------------
// Round-8 counters: k_edges was atomic-write-through-BW-bound (1.6M RMW ->
// 50 MB at 822 GB/s). Merging the cnt pass into the scatter via a 64-slot
// bucket array removes 0.8M atomics, the entire rowptr scan, and one full
// read of edge_index. Bucket content is a fixed multiset; k_sortdinv
// canonicalizes order -> deterministic.

__global__ void k_scatter2(const int* __restrict__ ei, int E,
                           int* deg, int* cnt, int* slots) {
    int e = blockIdx.x * blockDim.x + threadIdx.x;
    if (e >= E) return;
    int s = ei[e], d = ei[E + e];
    if (s != d) atomicAdd(&deg[s], 1);
    int pos = atomicAdd(&cnt[d], 1);
    if (pos < SLOT) slots[(size_t)d * SLOT + pos] = s;   // overflow provably impossible
}

// canonicalize bucket order (determinism) + dinv — one WAVE per node.
__global__ __launch_bounds__(256) void k_sortdinv(
    int* slots, const int* __restrict__ cnt,
    const int* __restrict__ deg, float* dinv, int N)
{
    int wid = (blockIdx.x * 256 + threadIdx.x) >> 6;
    int lane = threadIdx.x & 63;
    if (wid >= N) return;
    int d = min(cnt[wid], SLOT);
    int base = wid * SLOT;
    if (d > 1) {
        int val = (lane < d) ? slots[base + lane] : INT_MAX;
#pragma unroll
        for (int k = 2; k <= 64; k <<= 1) {
#pragma unroll
            for (int j = k >> 1; j > 0; j >>= 1) {
                int other = __shfl_xor(val, j, 64);
                bool asc = ((lane & k) == 0);
                bool lower = ((lane & j) == 0);
                bool keepMin = (asc == lower);
                val = keepMin ? min(val, other) : max(val, other);
            }
        }
        if (lane < d) slots[base + lane] = val;
    }
    if (lane == 0) {
        int dg = deg[wid];
        dinv[wid] = dg > 0 ? 1.0f / sqrtf((float)dg) : 0.0f;
    }
}

// ---------------- pass 1: NodeInformationScore + sum_neigh (one fused gather) ----------------
// fp32 path — deterministic score accumulation (sel decisions depend on it).

__global__ __launch_bounds__(256) void k_pass1(
    const float* __restrict__ utx, const int* __restrict__ cnt,
    const int* __restrict__ slots, const float* __restrict__ dinv,
    float* __restrict__ score, float* __restrict__ sumn, int N)
{
    int wid = (blockIdx.x * 256 + threadIdx.x) >> 6;
    int lane = threadIdx.x & 63;
    if (wid >= N) return;
    float dn = dinv[wid];
    int b0 = wid * SLOT;
    int b1 = b0 + min(cnt[wid], SLOT);
    float accn = 0.f, accs = 0.f;
    for (int e0 = b0; e0 < b1; e0 += 8) {
        int sv_l = 0; float wv_l = 0.f, wn_l = 0.f;
        if (lane < 8) {
            int e  = e0 + lane;
            int ec = e < b1 ? e : (b1 - 1);
            int cs = slots[ec];
            sv_l = cs;
            bool ok = e < b1;
            wn_l = ok ? 1.0f : 0.0f;
            wv_l = (ok && cs != wid) ? dn * dinv[cs] : 0.0f;   // self-loop w=0
        }
#pragma unroll
        for (int i = 0; i < 8; ++i) {
            int   s = __builtin_amdgcn_readlane(sv_l, i);
            float w = rdlane_f(wv_l, i);
            float n = rdlane_f(wn_l, i);
            float v = utx[(size_t)s * 64 + lane];
            accn += w * v;
            accs += n * v;
        }
    }
    float info = utx[(size_t)wid * 64 + lane] - accn;
    float sc = wredsum(fabsf(info));
    sumn[(size_t)wid * 64 + lane] = accs;
    if (lane == 0) score[wid] = sc;
}

// ---------------- exact k-th largest via 4-pass 8-bit radix select ----------------

__global__ __launch_bounds__(256) void k_hist8(
    const float* __restrict__ score, unsigned* __restrict__ hist,
    const unsigned* __restrict__ scal, int N, int pass)
{
    __shared__ unsigned lh[256];
    int tid = threadIdx.x;
    lh[tid] = 0;
    __syncthreads();
    int n = blockIdx.x * 256 + tid;
    if (n < N) {
        unsigned bits = __float_as_uint(score[n]);   // score>=0 -> bit order == value order
        bool active = (pass == 0) || (((bits ^ scal[0]) >> (32 - 8 * pass)) == 0u);
        if (active) atomicAdd(&lh[(bits >> (24 - 8 * pass)) & 0xFFu], 1u);
    }
    __syncthreads();
    unsigned c = lh[tid];
    if (c) atomicAdd(&hist[tid], c);
}

__global__ __launch_bounds__(256) void k_pick8(
    const unsigned* __restrict__ hist, unsigned* scal, int K, int pass)
{
    __shared__ unsigned h[256];
    int t = threadIdx.x;
    h[t] = hist[t];
    __syncthreads();
    if (t == 0) {
        unsigned R = (pass == 0) ? (unsigned)K : scal[1];
        unsigned acc = 0;
        int B = 0;
        for (int bin = 255; bin >= 0; --bin) {       // descending: k-th LARGEST
            if (acc + h[bin] >= R) { B = bin; break; }
            acc += h[bin];
        }
        unsigned prefix = (pass == 0) ? 0u : scal[0];
        scal[0] = prefix | ((unsigned)B << (24 - 8 * pass));
        scal[1] = R - acc;
        if (pass == 3) scal[2] = scal[0];            // exact T bit pattern
    }
}

__global__ void k_sel(const float* __restrict__ score, const unsigned* __restrict__ scal,
                      float* sel, int N) {
    int n = blockIdx.x * blockDim.x + threadIdx.x;
    if (n >= N) return;
    float T = __uint_as_float(scal[2]);
    sel[n] = (score[n] > T) ? 1.0f : 0.0f;       // strict >, matches reference
}

// ---------------- sum_sel via correction: sums = sumn - sum_{sel==0} utx ----------------

__global__ __launch_bounds__(256) void k_sums_corr(
    const unsigned short* __restrict__ utx16, const int* __restrict__ cnt,
    const int* __restrict__ slots, const float* __restrict__ sel,
    const float* __restrict__ sumn, float* __restrict__ sums, int N)
{
    int wid = (blockIdx.x * 256 + threadIdx.x) >> 6;
    int lane = threadIdx.x & 63;
    if (wid >= N) return;
    int b0 = wid * SLOT;
    int b1 = b0 + min(cnt[wid], SLOT);
    float corr = 0.f;
    for (int e0 = b0; e0 < b1; e0 += 8) {
        int sv_l = 0; float w_l = 0.f;
        if (lane < 8) {
            int e  = e0 + lane;
            int ec = e < b1 ? e : (b1 - 1);
            int cs = slots[ec];
            sv_l = cs;
            w_l = (e < b1) ? (1.0f - sel[cs]) : 0.0f;   // 1 when NOT selected
        }
#pragma unroll
        for (int i = 0; i < 8; ++i) {
            float w = rdlane_f(w_l, i);
            int   s = __builtin_amdgcn_readlane(sv_l, i);
            if (w != 0.f)                                // wave-uniform branch
                corr += bf2f(utx16[(size_t)s * 64 + lane]);
        }
    }
    size_t o = (size_t)wid * 64 + lane;
    sums[o] = sumn[o] - corr;
}

// ---------------- wsel = sel * sigmoid(logmap0(hyp_linear(hyp_sums, beta_W, beta_b))) ----------------

__global__ __launch_bounds__(256) void k_beta(
    const float* __restrict__ sumn, const float* __restrict__ sums,
    const float* __restrict__ beta_W, const float* __restrict__ beta_b,
    const float* __restrict__ sel, float* __restrict__ wsel, int N)
{
    int wid = (blockIdx.x * 256 + threadIdx.x) >> 6;
    int lane = threadIdx.x & 63;
    if (wid >= N) return;
    // concat = [sum_sel, sum_neigh] (128 dims; lane holds dims lane and lane+64)
    float u0 = sums[(size_t)wid * 64 + lane];
    float u1 = sumn[(size_t)wid * 64 + lane];
    // hyp_sums = proj(expmap0(concat))
    float un = fmaxf(sqrtf(wredsum(u0 * u0 + u1 * u1)), MINNORM);
    float f = tanhf(un) / un;
    float h0 = f * u0, h1 = f * u1;
    float hn = fmaxf(sqrtf(wredsum(h0 * h0 + h1 * h1)), MINNORM);
    if (hn > MAXNORM) { float sc = MAXNORM / hn; h0 *= sc; h1 *= sc; }
    // mobius_matvec(beta_W [1,128], h) -> scalar
    float xn = fmaxf(sqrtf(wredsum(h0 * h0 + h1 * h1)), MINNORM);
    float mx = wredsum(h0 * beta_W[lane] + h1 * beta_W[64 + lane]);
    float mxn = fmaxf(fabsf(mx), MINNORM);
    float res = tanhf(mxn / xn * artanh_pos(xn)) * mx / mxn;
    float rn = fmaxf(fabsf(res), MINNORM);
    if (rn > MAXNORM) res = res / rn * MAXNORM;
    // hb = proj(expmap0(beta_b)) (scalar)
    float bb = beta_b[0];
    float bn = fmaxf(fabsf(bb), MINNORM);
    float hb = tanhf(bn) / bn * bb;
    float hbn = fmaxf(fabsf(hb), MINNORM);
    if (hbn > MAXNORM) hb = hb / hbn * MAXNORM;
    // mobius_add (1-dim)
    float x2 = res * res, y2 = hb * hb, xy = res * hb;
    float num = (1.f + 2.f * xy + y2) * res + (1.f - x2) * hb;
    float den = 1.f + 2.f * xy + x2 * y2;
    float p = num / fmaxf(den, MINNORM);
    float pn = fmaxf(fabsf(p), MINNORM);
    if (pn > MAXNORM) p = p / pn * MAXNORM;
    // logmap0 (1-dim) + sigmoid, pre-multiplied by sel gate
    float qn = fmaxf(fabsf(p), MINNORM);
    float lg = artanh_pos(qn) * p / qn;
    float w = 1.f / (1.f + expf(-lg));
    if (lane == 0) wsel[wid] = w * sel[wid];
}

// ---------------- A_x gather (bf16, lane-trick) + relu + expmap0/proj ----------------

__global__ __launch_bounds__(256) void k_axout(
    const float* __restrict__ utx, const unsigned short* __restrict__ utx16,
    const int* __restrict__ cnt, const int* __restrict__ slots,
    const float* __restrict__ wsel, float* __restrict__ out, int N)
{
    int wid = (blockIdx.x * 256 + threadIdx.x) >> 6;
    int lane = threadIdx.x & 63;
    if (wid >= N) return;
    int b0 = wid * SLOT;
    int b1 = b0 + min(cnt[wid], SLOT);
    float acc = 0.f;
    for (int e0 = b0; e0 < b1; e0 += 8) {
        int sv_l = 0; float w_l = 0.f;
        if (lane < 8) {
            int e  = e0 + lane;
            int ec = e < b1 ? e : (b1 - 1);
            int cs = slots[ec];
            sv_l = cs;
            w_l = (e < b1) ? wsel[cs] : 0.0f;    // wsel already includes sel gate
        }
#pragma unroll
        for (int i = 0; i < 8; ++i) {
            int   s = __builtin_amdgcn_readlane(sv_l, i);
            float w = rdlane_f(w_l, i);
            acc += w * bf2f(utx16[(size_t)s * 64 + lane]);
        }
    }
    float a = fmaxf(acc, 0.f);                               // relu AFTER aggregation
    float u = utx[(size_t)wid * 64 + lane] + a;              // own row stays fp32
    float un = fmaxf(sqrtf(wredsum(u * u)), MINNORM);
    float o = tanhf(un) / un * u;                            // expmap0
    float on = fmaxf(sqrtf(wredsum(o * o)), MINNORM);
    if (on > MAXNORM) o *= MAXNORM / on;                     // proj
    out[(size_t)wid * 64 + lane] = o;
}

// ---------------- launch ----------------

extern "C" void kernel_launch(void* const* d_in, const int* in_sizes, int n_in,
                              void* d_out, int out_size, void* d_ws, size_t ws_size,
                              hipStream_t stream)
{
    const float* x      = (const float*)d_in[0];
    const float* W      = (const float*)d_in[1];
    const float* b      = (const float*)d_in[2];
    const float* beta_W = (const float*)d_in[3];
    const float* beta_b = (const float*)d_in[4];
    const int*   ei     = (const int*)d_in[5];

    const int N = in_sizes[0] / 128;
    const int E = in_sizes[5] / 2;
    const int K = (int)((double)N * 0.75);
    float* out = (float*)d_out;

    char* ws = (char*)d_ws;
    size_t off = 0;
    auto alloc = [&](size_t bytes) -> void* {
        void* p = ws + off;
        off = (off + bytes + 255) & ~(size_t)255;
        return p;
    };
    float*          utx    = (float*)alloc((size_t)N * 64 * 4);
    unsigned short* utx16  = (unsigned short*)alloc((size_t)N * 64 * 2);
    float*          sumn   = (float*)alloc((size_t)N * 64 * 4);
    float*          sums   = (float*)alloc((size_t)N * 64 * 4);
    float*          score  = (float*)alloc((size_t)N * 4);
    float*          dinv   = (float*)alloc((size_t)N * 4);
    float*          sel    = (float*)alloc((size_t)N * 4);
    float*          wsel   = (float*)alloc((size_t)N * 4);
    int*            deg    = (int*)alloc((size_t)N * 4);
    int*            cnt    = (int*)alloc((size_t)N * 4);
    int*            slots  = (int*)alloc((size_t)N * SLOT * 4);   // 12.8 MB
    unsigned*       hist8  = (unsigned*)alloc(4 * 256 * 4);       // 4 passes x 256 bins
    unsigned*       scal   = (unsigned*)alloc(64);
    if (off > ws_size) return;  // workspace too small (should not happen)

    hipMemsetAsync(deg,   0, (size_t)N * 4, stream);
    hipMemsetAsync(cnt,   0, (size_t)N * 4, stream);
    hipMemsetAsync(hist8, 0, 4 * 256 * 4, stream);

    int gE  = (E + 255) / 256;
    int gN  = (N + 255) / 256;
    int gW  = (N + 3) / 4;           // wave-per-node kernels
    int gLin = (N + 63) / 64;        // k_linear: one 64-row tile per block, 4 K-split waves

    k_linear<<<gLin, 256, 0, stream>>>(x, W, b, utx, utx16, N);
    k_scatter2<<<gE, 256, 0, stream>>>(ei, E, deg, cnt, slots);
    k_sortdinv<<<gW, 256, 0, stream>>>(slots, cnt, deg, dinv, N);
    k_pass1<<<gW, 256, 0, stream>>>(utx, cnt, slots, dinv, score, sumn, N);
    for (int pass = 0; pass < 4; ++pass) {
        k_hist8<<<gN, 256, 0, stream>>>(score, hist8 + 256 * pass, scal, N, pass);
        k_pick8<<<1, 256, 0, stream>>>(hist8 + 256 * pass, scal, K, pass);
    }
    k_sel<<<gN, 256, 0, stream>>>(score, scal, sel, N);
    k_sums_corr<<<gW, 256, 0, stream>>>(utx16, cnt, slots, sel, sumn, sums, N);
    k_beta<<<gW, 256, 0, stream>>>(sumn, sums, beta_W, beta_b, sel, wsel, N);
    k_axout<<<gW, 256, 0, stream>>>(utx, utx16, cnt, slots, wsel, out, N);
}